// Round 3
// baseline (436.384 us; speedup 1.0000x reference)
//
#include <hip/hip_runtime.h>
#include <cmath>

// loss = bd * (A*K - B),  K = s + log(C - bd) - log(sd + C)
// A = EPS * sum_t a(m_t), B = EPS * sum_t a(m_t)*c(m_t)  (input-independent scalars)

__global__ __launch_bounds__(256) void diffeq_kl_kernel(
    const float4* __restrict__ bd4,
    const float4* __restrict__ s4,
    const float4* __restrict__ sd4,
    float4* __restrict__ out4,
    int n4, float A, float B)
{
    const float C = 0.01f;
    int idx = blockIdx.x * blockDim.x + threadIdx.x;
    int stride = gridDim.x * blockDim.x;
    for (int i = idx; i < n4; i += stride) {
        float4 b  = bd4[i];
        float4 sv = s4[i];
        float4 dv = sd4[i];
        float4 o;
        {
            float K = sv.x + __builtin_logf(C - b.x) - __builtin_logf(dv.x + C);
            o.x = b.x * fmaf(A, K, -B);
        }
        {
            float K = sv.y + __builtin_logf(C - b.y) - __builtin_logf(dv.y + C);
            o.y = b.y * fmaf(A, K, -B);
        }
        {
            float K = sv.z + __builtin_logf(C - b.z) - __builtin_logf(dv.z + C);
            o.z = b.z * fmaf(A, K, -B);
        }
        {
            float K = sv.w + __builtin_logf(C - b.w) - __builtin_logf(dv.w + C);
            o.w = b.w * fmaf(A, K, -B);
        }
        out4[i] = o;
    }
}

extern "C" void kernel_launch(void* const* d_in, const int* in_sizes, int n_in,
                              void* d_out, int out_size, void* d_ws, size_t ws_size,
                              hipStream_t stream) {
    // Inputs (setup_inputs order):
    //   d_in[0] = b_phi_zt        (UNUSED by the math)
    //   d_in[1] = b_phi_zt_deriv
    //   d_in[2] = s_phi_zt
    //   d_in[3] = s_phi_zt_deriv
    const float* bd = (const float*)d_in[1];
    const float* s  = (const float*)d_in[2];
    const float* sd = (const float*)d_in[3];
    float* out = (float*)d_out;

    // Time-loop constants (pure host math; deterministic, identical every call).
    // T = 1000; t = 1..T-2; m = -1 + eps*t; a = -1/(m*log(-m)); c = log(-log(-m)).
    const double EPS = 0.001;
    double S1 = 0.0, S2 = 0.0;
    for (int t = 1; t <= 998; ++t) {
        double m = -1.0 + EPS * (double)t;
        double lm = std::log(-m);          // < 0
        double a = -1.0 / (m * lm);
        double c = std::log(-lm);
        S1 += a;
        S2 += a * c;
    }
    float A = (float)(EPS * S1);
    float B = (float)(EPS * S2);

    int n = out_size;            // 64*2048*256 = 33554432, divisible by 4
    int n4 = n / 4;
    int block = 256;
    int grid = (n4 + block - 1) / block;
    if (grid > 2048) grid = 2048;   // grid-stride; ~8 blocks/CU

    diffeq_kl_kernel<<<grid, block, 0, stream>>>(
        (const float4*)bd, (const float4*)s, (const float4*)sd,
        (float4*)out, n4, A, B);
}